// Round 9
// baseline (433.922 us; speedup 1.0000x reference)
//
#include <hip/hip_runtime.h>

typedef _Float16 f16x8 __attribute__((ext_vector_type(8)));
typedef _Float16 f16x4 __attribute__((ext_vector_type(4)));
typedef float    f32x4 __attribute__((ext_vector_type(4)));

#define THW 6272
#define CCH 1024
#define DI  512

__device__ __forceinline__ void gload16(const _Float16* g, _Float16* l)
{
    __builtin_amdgcn_global_load_lds(
        (const __attribute__((address_space(1))) void*)g,
        (__attribute__((address_space(3))) void*)l, 16, 0, 0);
}

// ---------------------------------------------------------------------------
// m97-structure NT GEMM (single-buffered core + LDS-roundtrip epilogue):
// C[M,N] = alpha*A[M,K]*Bt[N,K]^T (+bias_m/bias_n). A,Bt row-major K-contig.
// BMx128 tile, BK=64, 4 waves, global_load_lds(16B) into linear LDS,
// 2 barriers/K-step, bijective XCD swizzle. Flat 1-D grid gx*gy*gz,
// gz = 2*NKS (sample-fastest: n = zz&1, ks = zz>>1).
// Split-K: slice ks covers [ks*K, min(ks*K+K, Kfull)); C += zz*sCn.
// Epilogue: vals -> LDS tile (immediate-offset ds_write) -> coalesced
// vector global stores (f16x8 / f32x4) instead of 64 scalar stores.
// EXPP: val=exp(val), emit per-(row,64col) partial sums to psum.
// GNP:  emit per-block (sum, sumsq) into psum[wg*2].
// RSC:  scale val by row_scale[n*rows_ps + row].
// ---------------------------------------------------------------------------
template<typename OUT_T, int BM, bool BIAS_M, bool BIAS_N, bool EXPP, bool GNP, bool RSC>
__global__ __launch_bounds__(256, 3)
void gemm_nt(const _Float16* __restrict__ A, size_t lda, size_t sAn,
             const _Float16* __restrict__ Bt, size_t ldb, size_t sBn,
             OUT_T* __restrict__ C, size_t ldc, size_t sCn,
             int K, int Kfull, float alpha,
             const float* __restrict__ bias_m,
             const float* __restrict__ bias_n,
             float* __restrict__ psum,
             const float* __restrict__ row_scale,
             int rows_ps,
             int gx, int gy)
{
    constexpr int MF = BM / 32;
    __shared__ __align__(16) _Float16 smem[BM * 64 + 128 * 64];
    __shared__ float rs[4], rs2[4];
    _Float16* As = smem;
    _Float16* Bs = smem + BM * 64;
    const int tid  = threadIdx.x;
    const int lane = tid & 63;
    const int wave = tid >> 6;
    const int wr = wave >> 1, wc = wave & 1;

    // bijective chunked XCD swizzle (m204)
    const int nwg = gridDim.x;
    const int q = nwg >> 3, rr = nwg & 7;
    const int xcd = blockIdx.x & 7, seq = blockIdx.x >> 3;
    const int wg = (xcd < rr ? xcd * (q + 1) : rr * (q + 1) + (xcd - rr) * q) + seq;
    const int zz  = wg / (gx * gy);
    const int rem = wg - zz * gx * gy;
    const int by  = rem / gx, bx = rem - by * gx;
    const int n   = zz & 1;        // sample
    const int ks  = zz >> 1;       // K-split index

    const int koff = ks * K;
    const int klen = (Kfull - koff < K) ? (Kfull - koff) : K;

    A  += (size_t)n * sAn + (size_t)by * BM * lda + koff;
    Bt += (size_t)n * sBn + (size_t)bx * 128 * ldb + koff;

    const int srow = lane >> 3, sk = (lane & 7) * 8;
    const _Float16* gA = A  + (size_t)(wave * (MF * 8) + srow) * lda + sk;
    const _Float16* gB = Bt + (size_t)(wave * 32 + srow) * ldb + sk;
    _Float16* lA = As + wave * (MF * 512) + lane * 8;
    _Float16* lB = Bs + wave * 2048 + lane * 8;

    const int r  = lane & 15;
    const int kg = lane >> 4;

    f32x4 acc[MF][4] = {};

    for (int kt = 0; kt < klen; kt += 64) {
#pragma unroll
        for (int i = 0; i < MF; i++)
            gload16(gA + (size_t)(i * 8) * lda, lA + i * 512);
#pragma unroll
        for (int i = 0; i < 4; i++)
            gload16(gB + (size_t)(i * 8) * ldb, lB + i * 512);
        gA += 64; gB += 64;
        __syncthreads();
#pragma unroll
        for (int kk = 0; kk < 2; kk++) {
            f16x8 af[MF], bf[4];
#pragma unroll
            for (int mf = 0; mf < MF; mf++)
                af[mf] = *(const f16x8*)(As + (wr * (BM / 2) + mf * 16 + r) * 64 + kk * 32 + kg * 8);
#pragma unroll
            for (int nf = 0; nf < 4; nf++)
                bf[nf] = *(const f16x8*)(Bs + (wc * 64 + nf * 16 + r) * 64 + kk * 32 + kg * 8);
#pragma unroll
            for (int mf = 0; mf < MF; mf++)
#pragma unroll
                for (int nf = 0; nf < 4; nf++)
                    acc[mf][nf] = __builtin_amdgcn_mfma_f32_16x16x32_f16(
                        af[mf], bf[nf], acc[mf][nf], 0, 0, 0);
        }
        __syncthreads();
    }

    C += (size_t)zz * sCn;
    float gs = 0.f, gs2 = 0.f;

    // compute final vals in-place in acc; EXPP psum + GNP register reductions
#pragma unroll
    for (int mf = 0; mf < MF; mf++) {
#pragma unroll
        for (int qi = 0; qi < 4; qi++) {
            size_t row = (size_t)by * BM + wr * (BM / 2) + mf * 16 + kg * 4 + qi;
            float bm = BIAS_M ? bias_m[row] : 0.f;
            float sc = RSC ? row_scale[(size_t)n * rows_ps + row] : 1.f;
            float rsum = 0.f;
#pragma unroll
            for (int nf = 0; nf < 4; nf++) {
                size_t col = (size_t)bx * 128 + wc * 64 + nf * 16 + r;
                float val = acc[mf][nf][qi] * alpha + bm + (BIAS_N ? bias_n[col] : 0.f);
                if (EXPP) { val = __expf(val); rsum += val; }
                else if (RSC) val *= sc;
                if (GNP) { gs += val; gs2 += val * val; }
                acc[mf][nf][qi] = val;
            }
            if (EXPP) {
                rsum += __shfl_xor(rsum, 1);
                rsum += __shfl_xor(rsum, 2);
                rsum += __shfl_xor(rsum, 4);
                rsum += __shfl_xor(rsum, 8);
                if (r == 0)
                    psum[((size_t)n * rows_ps + row) * 98 + bx * 2 + wc] = rsum;
            }
        }
    }
    if (GNP) {
        for (int o = 32; o; o >>= 1) {
            gs  += __shfl_xor(gs, o);
            gs2 += __shfl_xor(gs2, o);
        }
        if (lane == 0) { rs[wave] = gs; rs2[wave] = gs2; }
    }

    if constexpr (sizeof(OUT_T) == 2) {
        // fp16 out: full tile [BM][128] in LDS (reuses As/Bs), vector store
        _Float16* Ct = smem;
        const int cbase = (wr * (BM / 2) + kg * 4) * 128 + wc * 64 + r;
#pragma unroll
        for (int mf = 0; mf < MF; mf++)
#pragma unroll
            for (int qi = 0; qi < 4; qi++)
#pragma unroll
                for (int nf = 0; nf < 4; nf++)
                    Ct[cbase + (mf * 16 + qi) * 128 + nf * 16] = (_Float16)acc[mf][nf][qi];
        __syncthreads();
        if (GNP && tid == 0) {
            psum[(size_t)wg * 2]     = rs[0] + rs[1] + rs[2] + rs[3];
            psum[(size_t)wg * 2 + 1] = rs2[0] + rs2[1] + rs2[2] + rs2[3];
        }
#pragma unroll
        for (int it = 0; it < BM / 16; it++) {
            int idx = it * 256 + tid;
            int rowl = idx >> 4, cv = (idx & 15) * 8;
            *(f16x8*)(C + ((size_t)by * BM + rowl) * ldc + (size_t)bx * 128 + cv)
                = *(const f16x8*)(Ct + rowl * 128 + cv);
        }
    } else {
        // fp32 out: two 64-col halves through [BM][64] fp32 LDS
        float* Cf = (float*)smem;
#pragma unroll
        for (int h = 0; h < 2; h++) {
            if (wc == h) {
                const int cb = (wr * (BM / 2) + kg * 4) * 64 + r;
#pragma unroll
                for (int mf = 0; mf < MF; mf++)
#pragma unroll
                    for (int qi = 0; qi < 4; qi++)
#pragma unroll
                        for (int nf = 0; nf < 4; nf++)
                            Cf[cb + (mf * 16 + qi) * 64 + nf * 16] = acc[mf][nf][qi];
            }
            __syncthreads();
            if (GNP && h == 0 && tid == 0) {
                psum[(size_t)wg * 2]     = rs[0] + rs[1] + rs[2] + rs[3];
                psum[(size_t)wg * 2 + 1] = rs2[0] + rs2[1] + rs2[2] + rs2[3];
            }
#pragma unroll
            for (int it = 0; it < BM / 16; it++) {
                int idx = it * 256 + tid;
                int rowl = idx >> 4, cv = (idx & 15) * 4;
                *(f32x4*)(C + ((size_t)by * BM + rowl) * ldc + (size_t)bx * 128 + h * 64 + cv)
                    = *(const f32x4*)(Cf + rowl * 64 + cv);
            }
            if (h == 0) __syncthreads();
        }
    }
}

// ---------------------------------------------------------------------------
// inv[row] = 1 / sum_chunks psum[row][0..97]
// ---------------------------------------------------------------------------
__global__ __launch_bounds__(256)
void rowsum_inv(const float* __restrict__ psum, float* __restrict__ inv, int nrows)
{
    int rI = blockIdx.x * 256 + threadIdx.x;
    if (rI < nrows) {
        const float* p = psum + (size_t)rI * 98;
        float s = 0.f;
#pragma unroll 7
        for (int i = 0; i < 98; i++) s += p[i];
        inv[rI] = 1.f / s;
    }
}

// ---------------------------------------------------------------------------
// Ot[n][t0+t][d] = f16( sum_{ks=0..3} Op[ks*2+n][t][d] )   (Op fp16, normalized)
// ---------------------------------------------------------------------------
__global__ __launch_bounds__(256)
void combine4(const _Float16* __restrict__ Op, _Float16* __restrict__ Ot,
              int tr, int t0)
{
    const int per_n8 = tr * 64;                 // f16x8 vectors per sample
    int idx = blockIdx.x * 256 + threadIdx.x;
    if (idx >= 2 * per_n8) return;
    int n = idx / per_n8;
    int rem = idx - n * per_n8;
    int t = rem >> 6, d8 = rem & 63;
    const size_t slice = (size_t)tr * 512;
    float o[8] = {};
#pragma unroll
    for (int ks = 0; ks < 4; ks++) {
        f16x8 v = *(const f16x8*)(Op + (size_t)(ks * 2 + n) * slice + (size_t)rem * 8);
#pragma unroll
        for (int j = 0; j < 8; j++) o[j] += (float)v[j];
    }
    f16x8 w;
#pragma unroll
    for (int j = 0; j < 8; j++) w[j] = (_Float16)o[j];
    *(f16x8*)(Ot + ((size_t)(n * THW + t0 + t) * DI + d8 * 8)) = w;
}

// ---------------------------------------------------------------------------
__global__ __launch_bounds__(256)
void pack_weights(const float* __restrict__ wt, const float* __restrict__ wp,
                  const float* __restrict__ wg, const float* __restrict__ wo,
                  const float* __restrict__ bt, const float* __restrict__ bp,
                  _Float16* __restrict__ Wtp, _Float16* __restrict__ Wg,
                  _Float16* __restrict__ Wo, float* __restrict__ btp)
{
    int i = blockIdx.x * 256 + threadIdx.x;
    if (i < 512 * 1024) {
        Wtp[i]              = (_Float16)wt[i];
        Wtp[i + 512 * 1024] = (_Float16)wp[i];
        Wg[i]               = (_Float16)wg[i];
        Wo[i]               = (_Float16)wo[i];
    }
    if (i < 512) { btp[i] = bt[i]; btp[i + 512] = bp[i]; }
}

// ---------------------------------------------------------------------------
// xT[n, t, c] = f16(x[n, c, t])
// ---------------------------------------------------------------------------
__global__ __launch_bounds__(256)
void transpose_cast(const float* __restrict__ x, _Float16* __restrict__ xT)
{
    __shared__ float tile[32][33];
    const int n  = blockIdx.z;
    const int t0 = blockIdx.x * 32;
    const int c0 = blockIdx.y * 32;
    const int tx = threadIdx.x & 31, ty = threadIdx.x >> 5;
    const float* xp = x + ((size_t)n * CCH + c0) * THW + t0;
#pragma unroll
    for (int i = 0; i < 4; i++) {
        int c = ty + i * 8;
        tile[c][tx] = xp[(size_t)c * THW + tx];
    }
    __syncthreads();
    _Float16* op = xT + ((size_t)n * THW + t0) * CCH + c0;
#pragma unroll
    for (int i = 0; i < 4; i++) {
        int t = ty + i * 8;
        op[(size_t)t * CCH + tx] = (_Float16)tile[tx][t];
    }
}

// ---------------------------------------------------------------------------
// GroupNorm finalize from per-block partials + fused residual.
// ---------------------------------------------------------------------------
__global__ __launch_bounds__(256)
void reduce_final(const float* __restrict__ partials, float* __restrict__ stats, int nblk)
{
    const int n = blockIdx.x;
    float s = 0.f, s2 = 0.f;
    for (int i = threadIdx.x; i < nblk; i += 256) {
        s  += partials[((size_t)n * nblk + i) * 2];
        s2 += partials[((size_t)n * nblk + i) * 2 + 1];
    }
    for (int o = 32; o; o >>= 1) { s += __shfl_xor(s, o); s2 += __shfl_xor(s2, o); }
    __shared__ float rs[4], rs2[4];
    if ((threadIdx.x & 63) == 0) { rs[threadIdx.x >> 6] = s; rs2[threadIdx.x >> 6] = s2; }
    __syncthreads();
    if (threadIdx.x == 0) {
        float S1 = rs[0] + rs[1] + rs[2] + rs[3];
        float S2 = rs2[0] + rs2[1] + rs2[2] + rs2[3];
        const float invc = 1.f / ((float)CCH * (float)THW);
        float mean = S1 * invc;
        float var  = S2 * invc - mean * mean;
        stats[n * 2]     = mean;
        stats[n * 2 + 1] = rsqrtf(var + 1e-5f);
    }
}

__global__ __launch_bounds__(256)
void final_residual(const float* __restrict__ x, float* __restrict__ pc_out,
                    const float* __restrict__ stats, size_t total4)
{
    const size_t per_n4 = (size_t)CCH * THW / 4;
    for (size_t i = (size_t)blockIdx.x * 256 + threadIdx.x; i < total4;
         i += (size_t)gridDim.x * 256) {
        int n = (int)(i / per_n4);
        float mean = stats[n * 2], rstd = stats[n * 2 + 1];
        f32x4 xv = ((const f32x4*)x)[i];
        f32x4 pv = ((f32x4*)pc_out)[i];
        f32x4 ov;
#pragma unroll
        for (int j = 0; j < 4; j++) ov[j] = xv[j] + (pv[j] - mean) * rstd;
        ((f32x4*)pc_out)[i] = ov;
    }
}

// ---------------------------------------------------------------------------
extern "C" void kernel_launch(void* const* d_in, const int* in_sizes, int n_in,
                              void* d_out, int out_size, void* d_ws, size_t ws_size,
                              hipStream_t stream)
{
    const float* x  = (const float*)d_in[0];
    const float* wt = (const float*)d_in[1];
    const float* bt = (const float*)d_in[2];
    const float* wp = (const float*)d_in[3];
    const float* bp = (const float*)d_in[4];
    const float* wg = (const float*)d_in[5];
    const float* bg = (const float*)d_in[6];
    const float* wo = (const float*)d_in[7];
    const float* bo = (const float*)d_in[8];
    float* out = (float*)d_out;

    char* ws = (char*)d_ws;
    size_t off = 0;
    auto alloc = [&](size_t b) -> void* {
        off = (off + 255) & ~(size_t)255;
        void* p = ws + off;
        off += b;
        return p;
    };

    _Float16* Wtp = (_Float16*)alloc((size_t)1024 * 1024 * 2);
    _Float16* Wg  = (_Float16*)alloc((size_t)512 * 1024 * 2);
    _Float16* Wo  = (_Float16*)alloc((size_t)1024 * 512 * 2);
    float*    btp = (float*)alloc(1024 * 4);
    _Float16* xT  = (_Float16*)alloc((size_t)2 * THW * CCH * 2);
    _Float16* tpg = (_Float16*)alloc((size_t)2 * THW * 1024 * 2);  // [n][t][theta|phi]
    _Float16* g   = (_Float16*)alloc((size_t)2 * DI * THW * 2);    // [n][d][t]
    _Float16* Ot  = (_Float16*)alloc((size_t)2 * THW * DI * 2);    // [n][t][d]
    float*    gnp   = (float*)alloc((size_t)784 * 2 * 4);          // out-GEMM block stats
    float*    stats = (float*)alloc(4 * 4);

    // exp(S) fp16 in ws; PV split-K=4 fp16 NORMALIZED partials in d_out.
    const size_t tile_bytes = (size_t)2 * 128 * (THW * 2 + 98 * 4 + 4);
    size_t avail = (ws_size > off + 256) ? ws_size - off - 256 : 0;
    int tiles_fit = (int)(avail / tile_bytes);
    if (tiles_fit < 1) tiles_fit = 1;
    if (tiles_fit > 49) tiles_fit = 49;
    int nch = (49 + tiles_fit - 1) / tiles_fit;
    int tpc = (49 + nch - 1) / nch;

    _Float16* S    = (_Float16*)alloc((size_t)2 * tpc * 128 * THW * 2);
    float*    psum = (float*)alloc((size_t)2 * tpc * 128 * 98 * 4);
    float*    inv  = (float*)alloc((size_t)2 * tpc * 128 * 4);
    _Float16* Opart = (_Float16*)out;   // [8][tpc*128][512] fp16, fits 51.4 MB

    const size_t sXT = (size_t)THW * CCH;
    const size_t sG  = (size_t)DI * THW;

    pack_weights<<<2048, 256, 0, stream>>>(wt, wp, wg, wo, bt, bp, Wtp, Wg, Wo, btp);
    transpose_cast<<<dim3(THW / 32, CCH / 32, 2), 256, 0, stream>>>(x, xT);

    // theta|phi (t-major): tpg[t, m] = sum_c xT[t,c]*Wtp[m,c] + btp[m]
    gemm_nt<_Float16, 128, false, true, false, false, false><<<8 * 49 * 2, 256, 0, stream>>>(
        xT, CCH, sXT, Wtp, CCH, 0, tpg, 1024, sXT, CCH, CCH, 1.f,
        nullptr, btp, nullptr, nullptr, 0, 8, 49);

    // g (d-major): g[d, t] = sum_c Wg[d,c]*xT[t,c] + bg[d]
    gemm_nt<_Float16, 64, true, false, false, false, false><<<49 * 8 * 2, 256, 0, stream>>>(
        Wg, CCH, 0, xT, CCH, sXT, g, THW, sG, CCH, CCH, 1.f,
        bg, nullptr, nullptr, nullptr, 0, 49, 8);

    const float scale = 0.044194173824159216f;  // 512^-0.5
    for (int ch = 0; ch < nch; ch++) {
        int tile0 = ch * tpc;
        int tiles = (49 - tile0 < tpc) ? (49 - tile0) : tpc;
        size_t t0 = (size_t)tile0 * 128;
        int tchRows = tiles * 128;

        // expS[t,p] = exp(scale * sum_d theta[t,d]*phi[p,d]); psum partials
        gemm_nt<_Float16, 128, false, false, true, false, false><<<49 * tiles * 2, 256, 0, stream>>>(
            tpg + t0 * 1024, 1024, sXT, tpg + 512, 1024, sXT,
            S, THW, (size_t)tchRows * THW, DI, DI, scale,
            nullptr, nullptr, psum, nullptr, tchRows, 49, tiles);

        rowsum_inv<<<(2 * tchRows + 255) / 256, 256, 0, stream>>>(psum, inv, 2 * tchRows);

        // Opart[zz][t][d] = inv[t] * sum_{p in split ks} expS[t,p]*g[d,p]
        // split-K=4 (uneven: 1600,1600,1600,1472), normalized fp16 partials
        gemm_nt<_Float16, 128, false, false, false, false, true><<<4 * tiles * 8, 256, 0, stream>>>(
            S, THW, (size_t)tchRows * THW, g, THW, sG,
            Opart, DI, (size_t)tchRows * DI, 1600, THW, 1.f,
            nullptr, nullptr, nullptr, inv, tchRows, 4, tiles);

        // Ot[t,d] = f16( sum_ks Opart[ks*2+n][t][d] )
        combine4<<<(tchRows * 128 + 255) / 256, 256, 0, stream>>>(
            Opart, Ot, tchRows, (int)t0);
    }

    // Pc[c,t] = sum_d Wo[c,d]*Ot[t,d] + bo[c]; emits per-block GroupNorm stats
    gemm_nt<float, 128, true, false, false, true, false><<<49 * 8 * 2, 256, 0, stream>>>(
        Wo, DI, 0, Ot, DI, sG, out, THW, (size_t)CCH * THW, DI, DI, 1.f,
        bo, nullptr, gnp, nullptr, 0, 49, 8);

    reduce_final<<<2, 256, 0, stream>>>(gnp, stats, 392);
    final_residual<<<2048, 256, 0, stream>>>(x, out, stats, (size_t)2 * CCH * THW / 4);
}

// Round 10
// 425.736 us; speedup vs baseline: 1.0192x; 1.0192x over previous
//
#include <hip/hip_runtime.h>

typedef _Float16 f16x8 __attribute__((ext_vector_type(8)));
typedef _Float16 f16x4 __attribute__((ext_vector_type(4)));
typedef float    f32x4 __attribute__((ext_vector_type(4)));

#define THW 6272
#define CCH 1024
#define DI  512

__device__ __forceinline__ void gload16(const _Float16* g, _Float16* l)
{
    __builtin_amdgcn_global_load_lds(
        (const __attribute__((address_space(1))) void*)g,
        (__attribute__((address_space(3))) void*)l, 16, 0, 0);
}

// ---------------------------------------------------------------------------
// m97-structure NT GEMM with TRANSPOSED-STORE epilogue:
// math: T[M,N] = alpha*A[M,K]*Bt[N,K]^T; stored as C[col][row] (C is the
// [N-dim][M-dim] buffer, ldc = its row stride). Per lane the 4 acc values
// (qi) are M-contiguous -> one f16x4/f32x4 store per (mf,nf). A,Bt row-major
// K-contig. BMx128 tile, BK=64, 4 waves, global_load_lds(16B), 2 barriers/
// K-step, bijective XCD swizzle. Flat grid gx*gy*gz, gz = 2*NKS
// (n = zz&1, ks = zz>>1); split-K slice covers [ks*K, min(ks*K+K,Kfull)).
// BIAS_M: + bias_m[row] (f32x4 load). BIAS_N: + bias_n[col].
// EXPP: val=exp(val), per-col partial sums over this block's M-rows ->
//       psum[(n*rows_ps+col)*98 + by*2 + wr].
// GNP:  per-block (sum,sumsq) -> psum[wg*2].
// RSC:  val *= col_scale[n*rows_ps + col].
// ---------------------------------------------------------------------------
template<typename OUT_T, int BM, bool BIAS_M, bool BIAS_N, bool EXPP, bool GNP, bool RSC>
__global__ __launch_bounds__(256, 3)
void gemm_nt(const _Float16* __restrict__ A, size_t lda, size_t sAn,
             const _Float16* __restrict__ Bt, size_t ldb, size_t sBn,
             OUT_T* __restrict__ C, size_t ldc, size_t sCn,
             int K, int Kfull, float alpha,
             const float* __restrict__ bias_m,
             const float* __restrict__ bias_n,
             float* __restrict__ psum,
             const float* __restrict__ col_scale,
             int rows_ps,
             int gx, int gy)
{
    constexpr int MF = BM / 32;
    __shared__ _Float16 As[BM * 64];
    __shared__ _Float16 Bs[128 * 64];
    __shared__ float rs[4], rs2[4];
    const int tid  = threadIdx.x;
    const int lane = tid & 63;
    const int wave = tid >> 6;
    const int wr = wave >> 1, wc = wave & 1;

    // bijective chunked XCD swizzle (m204)
    const int nwg = gridDim.x;
    const int q = nwg >> 3, rr = nwg & 7;
    const int xcd = blockIdx.x & 7, seq = blockIdx.x >> 3;
    const int wg = (xcd < rr ? xcd * (q + 1) : rr * (q + 1) + (xcd - rr) * q) + seq;
    const int zz  = wg / (gx * gy);
    const int rem = wg - zz * gx * gy;
    const int by  = rem / gx, bx = rem - by * gx;
    const int n   = zz & 1;        // sample
    const int ks  = zz >> 1;       // K-split index

    const int koff = ks * K;
    const int klen = (Kfull - koff < K) ? (Kfull - koff) : K;

    A  += (size_t)n * sAn + (size_t)by * BM * lda + koff;
    Bt += (size_t)n * sBn + (size_t)bx * 128 * ldb + koff;

    const int srow = lane >> 3, sk = (lane & 7) * 8;
    const _Float16* gA = A  + (size_t)(wave * (MF * 8) + srow) * lda + sk;
    const _Float16* gB = Bt + (size_t)(wave * 32 + srow) * ldb + sk;
    _Float16* lA = As + wave * (MF * 512) + lane * 8;
    _Float16* lB = Bs + wave * 2048 + lane * 8;

    const int r  = lane & 15;
    const int kg = lane >> 4;

    f32x4 acc[MF][4] = {};

    for (int kt = 0; kt < klen; kt += 64) {
#pragma unroll
        for (int i = 0; i < MF; i++)
            gload16(gA + (size_t)(i * 8) * lda, lA + i * 512);
#pragma unroll
        for (int i = 0; i < 4; i++)
            gload16(gB + (size_t)(i * 8) * ldb, lB + i * 512);
        gA += 64; gB += 64;
        __syncthreads();
#pragma unroll
        for (int kk = 0; kk < 2; kk++) {
            f16x8 af[MF], bf[4];
#pragma unroll
            for (int mf = 0; mf < MF; mf++)
                af[mf] = *(const f16x8*)(As + (wr * (BM / 2) + mf * 16 + r) * 64 + kk * 32 + kg * 8);
#pragma unroll
            for (int nf = 0; nf < 4; nf++)
                bf[nf] = *(const f16x8*)(Bs + (wc * 64 + nf * 16 + r) * 64 + kk * 32 + kg * 8);
#pragma unroll
            for (int mf = 0; mf < MF; mf++)
#pragma unroll
                for (int nf = 0; nf < 4; nf++)
                    acc[mf][nf] = __builtin_amdgcn_mfma_f32_16x16x32_f16(
                        af[mf], bf[nf], acc[mf][nf], 0, 0, 0);
        }
        __syncthreads();
    }

    C += (size_t)zz * sCn;
    float gs = 0.f, gs2 = 0.f;
    const size_t rowb0 = (size_t)by * BM + wr * (BM / 2) + kg * 4;

#pragma unroll
    for (int nf = 0; nf < 4; nf++) {
        const size_t col = (size_t)bx * 128 + wc * 64 + nf * 16 + r;
        const float bn = BIAS_N ? bias_n[col] : 0.f;
        const float sc = RSC ? col_scale[(size_t)n * rows_ps + col] : 1.f;
        float rsum = 0.f;
        OUT_T* cp = C + col * ldc + rowb0;
#pragma unroll
        for (int mf = 0; mf < MF; mf++) {
            f32x4 bm4 = {0.f, 0.f, 0.f, 0.f};
            if (BIAS_M) bm4 = *(const f32x4*)(bias_m + rowb0 + mf * 16);
            float v[4];
#pragma unroll
            for (int qi = 0; qi < 4; qi++) {
                float val = acc[mf][nf][qi] * alpha + bm4[qi] + bn;
                if (EXPP) { val = __expf(val); rsum += val; }
                else if (RSC) val *= sc;
                if (GNP) { gs += val; gs2 += val * val; }
                v[qi] = val;
            }
            if constexpr (sizeof(OUT_T) == 2) {
                f16x4 o;
                o[0] = (_Float16)v[0]; o[1] = (_Float16)v[1];
                o[2] = (_Float16)v[2]; o[3] = (_Float16)v[3];
                *(f16x4*)(cp + mf * 16) = o;
            } else {
                f32x4 o;
                o[0] = v[0]; o[1] = v[1]; o[2] = v[2]; o[3] = v[3];
                *(f32x4*)(cp + mf * 16) = o;
            }
        }
        if (EXPP) {
            rsum += __shfl_xor(rsum, 16);
            rsum += __shfl_xor(rsum, 32);
            if (kg == 0)
                psum[((size_t)n * rows_ps + col) * 98 + by * 2 + wr] = rsum;
        }
    }
    if (GNP) {
        for (int o = 32; o; o >>= 1) {
            gs  += __shfl_xor(gs, o);
            gs2 += __shfl_xor(gs2, o);
        }
        if (lane == 0) { rs[wave] = gs; rs2[wave] = gs2; }
        __syncthreads();
        if (tid == 0) {
            psum[(size_t)wg * 2]     = rs[0] + rs[1] + rs[2] + rs[3];
            psum[(size_t)wg * 2 + 1] = rs2[0] + rs2[1] + rs2[2] + rs2[3];
        }
    }
}

// ---------------------------------------------------------------------------
// inv[row] = 1 / sum_chunks psum[row][0..97]
// ---------------------------------------------------------------------------
__global__ __launch_bounds__(256)
void rowsum_inv(const float* __restrict__ psum, float* __restrict__ inv, int nrows)
{
    int rI = blockIdx.x * 256 + threadIdx.x;
    if (rI < nrows) {
        const float* p = psum + (size_t)rI * 98;
        float s = 0.f;
#pragma unroll 7
        for (int i = 0; i < 98; i++) s += p[i];
        inv[rI] = 1.f / s;
    }
}

// ---------------------------------------------------------------------------
// Ot[n][t0+t][d] = f16( sum_{ks=0..3} Op[ks*2+n][t][d] )   (Op fp16, normalized)
// ---------------------------------------------------------------------------
__global__ __launch_bounds__(256)
void combine4(const _Float16* __restrict__ Op, _Float16* __restrict__ Ot,
              int tr, int t0)
{
    const int per_n8 = tr * 64;                 // f16x8 vectors per sample
    int idx = blockIdx.x * 256 + threadIdx.x;
    if (idx >= 2 * per_n8) return;
    int n = idx / per_n8;
    int rem = idx - n * per_n8;
    int t = rem >> 6, d8 = rem & 63;
    const size_t slice = (size_t)tr * 512;
    float o[8] = {};
#pragma unroll
    for (int ks = 0; ks < 4; ks++) {
        f16x8 v = *(const f16x8*)(Op + (size_t)(ks * 2 + n) * slice + (size_t)rem * 8);
#pragma unroll
        for (int j = 0; j < 8; j++) o[j] += (float)v[j];
    }
    f16x8 w;
#pragma unroll
    for (int j = 0; j < 8; j++) w[j] = (_Float16)o[j];
    *(f16x8*)(Ot + ((size_t)(n * THW + t0 + t) * DI + d8 * 8)) = w;
}

// ---------------------------------------------------------------------------
__global__ __launch_bounds__(256)
void pack_weights(const float* __restrict__ wt, const float* __restrict__ wp,
                  const float* __restrict__ wg, const float* __restrict__ wo,
                  const float* __restrict__ bt, const float* __restrict__ bp,
                  _Float16* __restrict__ Wtp, _Float16* __restrict__ Wg,
                  _Float16* __restrict__ Wo, float* __restrict__ btp)
{
    int i = blockIdx.x * 256 + threadIdx.x;
    if (i < 512 * 1024) {
        Wtp[i]              = (_Float16)wt[i];
        Wtp[i + 512 * 1024] = (_Float16)wp[i];
        Wg[i]               = (_Float16)wg[i];
        Wo[i]               = (_Float16)wo[i];
    }
    if (i < 512) { btp[i] = bt[i]; btp[i + 512] = bp[i]; }
}

// ---------------------------------------------------------------------------
// xT[n, t, c] = f16(x[n, c, t])
// ---------------------------------------------------------------------------
__global__ __launch_bounds__(256)
void transpose_cast(const float* __restrict__ x, _Float16* __restrict__ xT)
{
    __shared__ float tile[32][33];
    const int n  = blockIdx.z;
    const int t0 = blockIdx.x * 32;
    const int c0 = blockIdx.y * 32;
    const int tx = threadIdx.x & 31, ty = threadIdx.x >> 5;
    const float* xp = x + ((size_t)n * CCH + c0) * THW + t0;
#pragma unroll
    for (int i = 0; i < 4; i++) {
        int c = ty + i * 8;
        tile[c][tx] = xp[(size_t)c * THW + tx];
    }
    __syncthreads();
    _Float16* op = xT + ((size_t)n * THW + t0) * CCH + c0;
#pragma unroll
    for (int i = 0; i < 4; i++) {
        int t = ty + i * 8;
        op[(size_t)t * CCH + tx] = (_Float16)tile[tx][t];
    }
}

// ---------------------------------------------------------------------------
// GroupNorm finalize from per-block partials + fused residual.
// ---------------------------------------------------------------------------
__global__ __launch_bounds__(256)
void reduce_final(const float* __restrict__ partials, float* __restrict__ stats, int nblk)
{
    const int n = blockIdx.x;
    float s = 0.f, s2 = 0.f;
    for (int i = threadIdx.x; i < nblk; i += 256) {
        s  += partials[((size_t)n * nblk + i) * 2];
        s2 += partials[((size_t)n * nblk + i) * 2 + 1];
    }
    for (int o = 32; o; o >>= 1) { s += __shfl_xor(s, o); s2 += __shfl_xor(s2, o); }
    __shared__ float rs[4], rs2[4];
    if ((threadIdx.x & 63) == 0) { rs[threadIdx.x >> 6] = s; rs2[threadIdx.x >> 6] = s2; }
    __syncthreads();
    if (threadIdx.x == 0) {
        float S1 = rs[0] + rs[1] + rs[2] + rs[3];
        float S2 = rs2[0] + rs2[1] + rs2[2] + rs2[3];
        const float invc = 1.f / ((float)CCH * (float)THW);
        float mean = S1 * invc;
        float var  = S2 * invc - mean * mean;
        stats[n * 2]     = mean;
        stats[n * 2 + 1] = rsqrtf(var + 1e-5f);
    }
}

__global__ __launch_bounds__(256)
void final_residual(const float* __restrict__ x, float* __restrict__ pc_out,
                    const float* __restrict__ stats, size_t total4)
{
    const size_t per_n4 = (size_t)CCH * THW / 4;
    for (size_t i = (size_t)blockIdx.x * 256 + threadIdx.x; i < total4;
         i += (size_t)gridDim.x * 256) {
        int n = (int)(i / per_n4);
        float mean = stats[n * 2], rstd = stats[n * 2 + 1];
        f32x4 xv = ((const f32x4*)x)[i];
        f32x4 pv = ((f32x4*)pc_out)[i];
        f32x4 ov;
#pragma unroll
        for (int j = 0; j < 4; j++) ov[j] = xv[j] + (pv[j] - mean) * rstd;
        ((f32x4*)pc_out)[i] = ov;
    }
}

// ---------------------------------------------------------------------------
extern "C" void kernel_launch(void* const* d_in, const int* in_sizes, int n_in,
                              void* d_out, int out_size, void* d_ws, size_t ws_size,
                              hipStream_t stream)
{
    const float* x  = (const float*)d_in[0];
    const float* wt = (const float*)d_in[1];
    const float* bt = (const float*)d_in[2];
    const float* wp = (const float*)d_in[3];
    const float* bp = (const float*)d_in[4];
    const float* wg = (const float*)d_in[5];
    const float* bg = (const float*)d_in[6];
    const float* wo = (const float*)d_in[7];
    const float* bo = (const float*)d_in[8];
    float* out = (float*)d_out;

    char* ws = (char*)d_ws;
    size_t off = 0;
    auto alloc = [&](size_t b) -> void* {
        off = (off + 255) & ~(size_t)255;
        void* p = ws + off;
        off += b;
        return p;
    };

    _Float16* Wtp = (_Float16*)alloc((size_t)1024 * 1024 * 2);
    _Float16* Wg  = (_Float16*)alloc((size_t)512 * 1024 * 2);
    _Float16* Wo  = (_Float16*)alloc((size_t)1024 * 512 * 2);
    float*    btp = (float*)alloc(1024 * 4);
    _Float16* xT  = (_Float16*)alloc((size_t)2 * THW * CCH * 2);
    _Float16* tpg = (_Float16*)alloc((size_t)2 * THW * 1024 * 2);  // [n][t][theta|phi]
    _Float16* g   = (_Float16*)alloc((size_t)2 * DI * THW * 2);    // [n][d][t]
    _Float16* Ot  = (_Float16*)alloc((size_t)2 * THW * DI * 2);    // [n][t][d]
    float*    gnp   = (float*)alloc((size_t)784 * 2 * 4);          // out-GEMM block stats
    float*    stats = (float*)alloc(4 * 4);

    // exp(S) fp16 in ws; PV split-K=4 fp16 NORMALIZED partials in d_out.
    const size_t tile_bytes = (size_t)2 * 128 * (THW * 2 + 98 * 4 + 4);
    size_t avail = (ws_size > off + 256) ? ws_size - off - 256 : 0;
    int tiles_fit = (int)(avail / tile_bytes);
    if (tiles_fit < 1) tiles_fit = 1;
    if (tiles_fit > 49) tiles_fit = 49;
    int nch = (49 + tiles_fit - 1) / tiles_fit;
    int tpc = (49 + nch - 1) / nch;

    _Float16* S    = (_Float16*)alloc((size_t)2 * tpc * 128 * THW * 2);
    float*    psum = (float*)alloc((size_t)2 * tpc * 128 * 98 * 4);
    float*    inv  = (float*)alloc((size_t)2 * tpc * 128 * 4);
    _Float16* Opart = (_Float16*)out;   // [8][tpc*128][512] fp16, fits 51.4 MB

    const size_t sXT = (size_t)THW * CCH;
    const size_t sG  = (size_t)DI * THW;

    pack_weights<<<2048, 256, 0, stream>>>(wt, wp, wg, wo, bt, bp, Wtp, Wg, Wo, btp);
    transpose_cast<<<dim3(THW / 32, CCH / 32, 2), 256, 0, stream>>>(x, xT);

    // theta|phi: math [m][t] = Wtp x xT^T; stored tpg[t][m]; bias btp on m (M side)
    gemm_nt<_Float16, 128, true, false, false, false, false><<<49 * 8 * 2, 256, 0, stream>>>(
        Wtp, CCH, 0, xT, CCH, sXT, tpg, 1024, sXT, CCH, CCH, 1.f,
        btp, nullptr, nullptr, nullptr, 0, 49, 8);

    // g: math [t][d] = xT x Wg^T (BM=64); stored g[d][t]; bias bg on d (N side)
    gemm_nt<_Float16, 64, false, true, false, false, false><<<4 * 98 * 2, 256, 0, stream>>>(
        xT, CCH, sXT, Wg, CCH, 0, g, THW, sG, CCH, CCH, 1.f,
        nullptr, bg, nullptr, nullptr, 0, 4, 98);

    const float scale = 0.044194173824159216f;  // 512^-0.5
    for (int ch = 0; ch < nch; ch++) {
        int tile0 = ch * tpc;
        int tiles = (49 - tile0 < tpc) ? (49 - tile0) : tpc;
        size_t t0 = (size_t)tile0 * 128;
        int tchRows = tiles * 128;

        // S: math [p][t-chunk] = phi x theta^T; stored S[t][p]; exp + per-col psum
        gemm_nt<_Float16, 128, false, false, true, false, false><<<tiles * 49 * 2, 256, 0, stream>>>(
            tpg + 512, 1024, sXT, tpg + t0 * 1024, 1024, sXT,
            S, THW, (size_t)tchRows * THW, DI, DI, scale,
            nullptr, nullptr, psum, nullptr, tchRows, tiles, 49);

        rowsum_inv<<<(2 * tchRows + 255) / 256, 256, 0, stream>>>(psum, inv, 2 * tchRows);

        // PV: math [d][t-chunk] = g x S^T, split-K=4 over p (1600x3+1472);
        // stored Op[zz][t][d], scaled by inv[t] (col side)
        gemm_nt<_Float16, 128, false, false, false, false, true><<<tiles * 4 * 8, 256, 0, stream>>>(
            g, THW, sG, S, THW, (size_t)tchRows * THW,
            Opart, DI, (size_t)tchRows * DI, 1600, THW, 1.f,
            nullptr, nullptr, nullptr, inv, tchRows, tiles, 4);

        // Ot[t,d] = f16( sum_ks Opart[ks*2+n][t][d] )
        combine4<<<(tchRows * 128 + 255) / 256, 256, 0, stream>>>(
            Opart, Ot, tchRows, (int)t0);
    }

    // out: math [t][c] = Ot x Wo^T; stored out[c][t]; bias bo on c (N side); GNP
    gemm_nt<float, 128, false, true, false, true, false><<<8 * 49 * 2, 256, 0, stream>>>(
        Ot, DI, sG, Wo, DI, 0, out, THW, (size_t)CCH * THW, DI, DI, 1.f,
        nullptr, bo, gnp, nullptr, 0, 8, 49);

    reduce_final<<<2, 256, 0, stream>>>(gnp, stats, 392);
    final_residual<<<2048, 256, 0, stream>>>(x, out, stats, (size_t)2 * CCH * THW / 4);
}

// Round 11
// 391.744 us; speedup vs baseline: 1.1077x; 1.0868x over previous
//
#include <hip/hip_runtime.h>

typedef _Float16 f16x8 __attribute__((ext_vector_type(8)));
typedef _Float16 f16x4 __attribute__((ext_vector_type(4)));
typedef float    f32x4 __attribute__((ext_vector_type(4)));

#define THW 6272
#define CCH 1024
#define DI  512

__device__ __forceinline__ void gload16(const _Float16* g, _Float16* l)
{
    __builtin_amdgcn_global_load_lds(
        (const __attribute__((address_space(1))) void*)g,
        (__attribute__((address_space(3))) void*)l, 16, 0, 0);
}

// ---------------------------------------------------------------------------
// m97-structure NT GEMM (single-buffered R8 core, 4 blocks/CU):
// C[M,N] = alpha*A[M,K]*Bt[N,K]^T (+bias_m/bias_n). A,Bt row-major K-contig.
// BMx128 tile, BK=64, 4 waves, global_load_lds(16B) into linear LDS,
// 2 barriers/K-step, bijective XCD swizzle. Flat 1-D grid gx*gy*gz,
// gz = 2*NKS (sample-fastest: n = zz&1, ks = zz>>1).
// Split-K: slice ks covers [ks*K, min(ks*K+K, Kfull)); C += zz*sCn.
// EXPP: write exp(val), emit per-(row,64col) partial sums to psum.
// GNP:  emit per-block (sum, sumsq) into psum[wg*2].
// RSC:  scale val by row_scale[n*rows_ps + row].
// ---------------------------------------------------------------------------
template<typename OUT_T, int BM, bool BIAS_M, bool BIAS_N, bool EXPP, bool GNP, bool RSC>
__global__ __launch_bounds__(256, 4)
void gemm_nt(const _Float16* __restrict__ A, size_t lda, size_t sAn,
             const _Float16* __restrict__ Bt, size_t ldb, size_t sBn,
             OUT_T* __restrict__ C, size_t ldc, size_t sCn,
             int K, int Kfull, float alpha,
             const float* __restrict__ bias_m,
             const float* __restrict__ bias_n,
             float* __restrict__ psum,
             const float* __restrict__ row_scale,
             int rows_ps,
             int gx, int gy)
{
    constexpr int MF = BM / 32;
    __shared__ _Float16 As[BM * 64];
    __shared__ _Float16 Bs[128 * 64];
    __shared__ float rs[4], rs2[4];
    const int tid  = threadIdx.x;
    const int lane = tid & 63;
    const int wave = tid >> 6;
    const int wr = wave >> 1, wc = wave & 1;

    // bijective chunked XCD swizzle (m204)
    const int nwg = gridDim.x;
    const int q = nwg >> 3, rr = nwg & 7;
    const int xcd = blockIdx.x & 7, seq = blockIdx.x >> 3;
    const int wg = (xcd < rr ? xcd * (q + 1) : rr * (q + 1) + (xcd - rr) * q) + seq;
    const int zz  = wg / (gx * gy);
    const int rem = wg - zz * gx * gy;
    const int by  = rem / gx, bx = rem - by * gx;
    const int n   = zz & 1;        // sample
    const int ks  = zz >> 1;       // K-split index

    const int koff = ks * K;
    const int klen = (Kfull - koff < K) ? (Kfull - koff) : K;

    A  += (size_t)n * sAn + (size_t)by * BM * lda + koff;
    Bt += (size_t)n * sBn + (size_t)bx * 128 * ldb + koff;

    const int srow = lane >> 3, sk = (lane & 7) * 8;
    const _Float16* gA = A  + (size_t)(wave * (MF * 8) + srow) * lda + sk;
    const _Float16* gB = Bt + (size_t)(wave * 32 + srow) * ldb + sk;
    _Float16* lA = As + wave * (MF * 512) + lane * 8;
    _Float16* lB = Bs + wave * 2048 + lane * 8;

    const int r  = lane & 15;
    const int kg = lane >> 4;

    f32x4 acc[MF][4] = {};

    for (int kt = 0; kt < klen; kt += 64) {
#pragma unroll
        for (int i = 0; i < MF; i++)
            gload16(gA + (size_t)(i * 8) * lda, lA + i * 512);
#pragma unroll
        for (int i = 0; i < 4; i++)
            gload16(gB + (size_t)(i * 8) * ldb, lB + i * 512);
        gA += 64; gB += 64;
        __syncthreads();
#pragma unroll
        for (int kk = 0; kk < 2; kk++) {
            f16x8 af[MF], bf[4];
#pragma unroll
            for (int mf = 0; mf < MF; mf++)
                af[mf] = *(const f16x8*)(As + (wr * (BM / 2) + mf * 16 + r) * 64 + kk * 32 + kg * 8);
#pragma unroll
            for (int nf = 0; nf < 4; nf++)
                bf[nf] = *(const f16x8*)(Bs + (wc * 64 + nf * 16 + r) * 64 + kk * 32 + kg * 8);
#pragma unroll
            for (int mf = 0; mf < MF; mf++)
#pragma unroll
                for (int nf = 0; nf < 4; nf++)
                    acc[mf][nf] = __builtin_amdgcn_mfma_f32_16x16x32_f16(
                        af[mf], bf[nf], acc[mf][nf], 0, 0, 0);
        }
        __syncthreads();
    }

    C += (size_t)zz * sCn;
    float gs = 0.f, gs2 = 0.f;

#pragma unroll
    for (int mf = 0; mf < MF; mf++) {
#pragma unroll
        for (int qi = 0; qi < 4; qi++) {
            size_t row = (size_t)by * BM + wr * (BM / 2) + mf * 16 + kg * 4 + qi;
            float bm = BIAS_M ? bias_m[row] : 0.f;
            float sc = RSC ? row_scale[(size_t)n * rows_ps + row] : 1.f;
            float rsum = 0.f;
#pragma unroll
            for (int nf = 0; nf < 4; nf++) {
                size_t col = (size_t)bx * 128 + wc * 64 + nf * 16 + r;
                float val = acc[mf][nf][qi] * alpha + bm + (BIAS_N ? bias_n[col] : 0.f);
                if (EXPP) { val = __expf(val); rsum += val; }
                else if (RSC) val *= sc;
                if (GNP) { gs += val; gs2 += val * val; }
                C[row * ldc + col] = (OUT_T)val;
            }
            if (EXPP) {
                rsum += __shfl_xor(rsum, 1);
                rsum += __shfl_xor(rsum, 2);
                rsum += __shfl_xor(rsum, 4);
                rsum += __shfl_xor(rsum, 8);
                if (r == 0)
                    psum[((size_t)n * rows_ps + row) * 98 + bx * 2 + wc] = rsum;
            }
        }
    }
    if (GNP) {
        for (int o = 32; o; o >>= 1) {
            gs  += __shfl_xor(gs, o);
            gs2 += __shfl_xor(gs2, o);
        }
        if (lane == 0) { rs[wave] = gs; rs2[wave] = gs2; }
        __syncthreads();
        if (tid == 0) {
            psum[(size_t)wg * 2]     = rs[0] + rs[1] + rs[2] + rs[3];
            psum[(size_t)wg * 2 + 1] = rs2[0] + rs2[1] + rs2[2] + rs2[3];
        }
    }
}

// ---------------------------------------------------------------------------
// inv[row] = 1 / sum_chunks psum[row][0..97]
// ---------------------------------------------------------------------------
__global__ __launch_bounds__(256)
void rowsum_inv(const float* __restrict__ psum, float* __restrict__ inv, int nrows)
{
    int rI = blockIdx.x * 256 + threadIdx.x;
    if (rI < nrows) {
        const float* p = psum + (size_t)rI * 98;
        float s = 0.f;
#pragma unroll 7
        for (int i = 0; i < 98; i++) s += p[i];
        inv[rI] = 1.f / s;
    }
}

// ---------------------------------------------------------------------------
// Ot[n][t0+t][d] = f16( sum_{ks=0..3} Op[ks*2+n][t][d] )   (Op fp16, normalized)
// ---------------------------------------------------------------------------
__global__ __launch_bounds__(256)
void combine4(const _Float16* __restrict__ Op, _Float16* __restrict__ Ot,
              int tr, int t0)
{
    const int per_n8 = tr * 64;                 // f16x8 vectors per sample
    int idx = blockIdx.x * 256 + threadIdx.x;
    if (idx >= 2 * per_n8) return;
    int n = idx / per_n8;
    int rem = idx - n * per_n8;
    int t = rem >> 6, d8 = rem & 63;
    const size_t slice = (size_t)tr * 512;
    float o[8] = {};
#pragma unroll
    for (int ks = 0; ks < 4; ks++) {
        f16x8 v = *(const f16x8*)(Op + (size_t)(ks * 2 + n) * slice + (size_t)rem * 8);
#pragma unroll
        for (int j = 0; j < 8; j++) o[j] += (float)v[j];
    }
    f16x8 w;
#pragma unroll
    for (int j = 0; j < 8; j++) w[j] = (_Float16)o[j];
    *(f16x8*)(Ot + ((size_t)(n * THW + t0 + t) * DI + d8 * 8)) = w;
}

// ---------------------------------------------------------------------------
__global__ __launch_bounds__(256)
void pack_weights(const float* __restrict__ wt, const float* __restrict__ wp,
                  const float* __restrict__ wg, const float* __restrict__ wo,
                  const float* __restrict__ bt, const float* __restrict__ bp,
                  _Float16* __restrict__ Wtp, _Float16* __restrict__ Wg,
                  _Float16* __restrict__ Wo, float* __restrict__ btp)
{
    int i = blockIdx.x * 256 + threadIdx.x;
    if (i < 512 * 1024) {
        Wtp[i]              = (_Float16)wt[i];
        Wtp[i + 512 * 1024] = (_Float16)wp[i];
        Wg[i]               = (_Float16)wg[i];
        Wo[i]               = (_Float16)wo[i];
    }
    if (i < 512) { btp[i] = bt[i]; btp[i + 512] = bp[i]; }
}

// ---------------------------------------------------------------------------
// xT[n, t, c] = f16(x[n, c, t])
// ---------------------------------------------------------------------------
__global__ __launch_bounds__(256)
void transpose_cast(const float* __restrict__ x, _Float16* __restrict__ xT)
{
    __shared__ float tile[32][33];
    const int n  = blockIdx.z;
    const int t0 = blockIdx.x * 32;
    const int c0 = blockIdx.y * 32;
    const int tx = threadIdx.x & 31, ty = threadIdx.x >> 5;
    const float* xp = x + ((size_t)n * CCH + c0) * THW + t0;
#pragma unroll
    for (int i = 0; i < 4; i++) {
        int c = ty + i * 8;
        tile[c][tx] = xp[(size_t)c * THW + tx];
    }
    __syncthreads();
    _Float16* op = xT + ((size_t)n * THW + t0) * CCH + c0;
#pragma unroll
    for (int i = 0; i < 4; i++) {
        int t = ty + i * 8;
        op[(size_t)t * CCH + tx] = (_Float16)tile[tx][t];
    }
}

// ---------------------------------------------------------------------------
// GroupNorm finalize from per-block partials + fused residual.
// ---------------------------------------------------------------------------
__global__ __launch_bounds__(256)
void reduce_final(const float* __restrict__ partials, float* __restrict__ stats, int nblk)
{
    const int n = blockIdx.x;
    float s = 0.f, s2 = 0.f;
    for (int i = threadIdx.x; i < nblk; i += 256) {
        s  += partials[((size_t)n * nblk + i) * 2];
        s2 += partials[((size_t)n * nblk + i) * 2 + 1];
    }
    for (int o = 32; o; o >>= 1) { s += __shfl_xor(s, o); s2 += __shfl_xor(s2, o); }
    __shared__ float rs[4], rs2[4];
    if ((threadIdx.x & 63) == 0) { rs[threadIdx.x >> 6] = s; rs2[threadIdx.x >> 6] = s2; }
    __syncthreads();
    if (threadIdx.x == 0) {
        float S1 = rs[0] + rs[1] + rs[2] + rs[3];
        float S2 = rs2[0] + rs2[1] + rs2[2] + rs2[3];
        const float invc = 1.f / ((float)CCH * (float)THW);
        float mean = S1 * invc;
        float var  = S2 * invc - mean * mean;
        stats[n * 2]     = mean;
        stats[n * 2 + 1] = rsqrtf(var + 1e-5f);
    }
}

__global__ __launch_bounds__(256)
void final_residual(const float* __restrict__ x, float* __restrict__ pc_out,
                    const float* __restrict__ stats, size_t total4)
{
    const size_t per_n4 = (size_t)CCH * THW / 4;
    for (size_t i = (size_t)blockIdx.x * 256 + threadIdx.x; i < total4;
         i += (size_t)gridDim.x * 256) {
        int n = (int)(i / per_n4);
        float mean = stats[n * 2], rstd = stats[n * 2 + 1];
        f32x4 xv = ((const f32x4*)x)[i];
        f32x4 pv = ((f32x4*)pc_out)[i];
        f32x4 ov;
#pragma unroll
        for (int j = 0; j < 4; j++) ov[j] = xv[j] + (pv[j] - mean) * rstd;
        ((f32x4*)pc_out)[i] = ov;
    }
}

// ---------------------------------------------------------------------------
extern "C" void kernel_launch(void* const* d_in, const int* in_sizes, int n_in,
                              void* d_out, int out_size, void* d_ws, size_t ws_size,
                              hipStream_t stream)
{
    const float* x  = (const float*)d_in[0];
    const float* wt = (const float*)d_in[1];
    const float* bt = (const float*)d_in[2];
    const float* wp = (const float*)d_in[3];
    const float* bp = (const float*)d_in[4];
    const float* wg = (const float*)d_in[5];
    const float* bg = (const float*)d_in[6];
    const float* wo = (const float*)d_in[7];
    const float* bo = (const float*)d_in[8];
    float* out = (float*)d_out;

    char* ws = (char*)d_ws;
    size_t off = 0;
    auto alloc = [&](size_t b) -> void* {
        off = (off + 255) & ~(size_t)255;
        void* p = ws + off;
        off += b;
        return p;
    };

    _Float16* Wtp = (_Float16*)alloc((size_t)1024 * 1024 * 2);
    _Float16* Wg  = (_Float16*)alloc((size_t)512 * 1024 * 2);
    _Float16* Wo  = (_Float16*)alloc((size_t)1024 * 512 * 2);
    float*    btp = (float*)alloc(1024 * 4);
    _Float16* xT  = (_Float16*)alloc((size_t)2 * THW * CCH * 2);
    _Float16* tpg = (_Float16*)alloc((size_t)2 * THW * 1024 * 2);  // [n][t][theta|phi]
    _Float16* g   = (_Float16*)alloc((size_t)2 * DI * THW * 2);    // [n][d][t]
    _Float16* Ot  = (_Float16*)alloc((size_t)2 * THW * DI * 2);    // [n][t][d]
    float*    gnp   = (float*)alloc((size_t)784 * 2 * 4);          // out-GEMM block stats
    float*    stats = (float*)alloc(4 * 4);

    // exp(S) fp16 in ws; PV split-K=4 fp16 NORMALIZED partials in d_out.
    const size_t tile_bytes = (size_t)2 * 128 * (THW * 2 + 98 * 4 + 4);
    size_t avail = (ws_size > off + 256) ? ws_size - off - 256 : 0;
    int tiles_fit = (int)(avail / tile_bytes);
    if (tiles_fit < 1) tiles_fit = 1;
    if (tiles_fit > 49) tiles_fit = 49;
    int nch = (49 + tiles_fit - 1) / tiles_fit;
    int tpc = (49 + nch - 1) / nch;

    _Float16* S    = (_Float16*)alloc((size_t)2 * tpc * 128 * THW * 2);
    float*    psum = (float*)alloc((size_t)2 * tpc * 128 * 98 * 4);
    float*    inv  = (float*)alloc((size_t)2 * tpc * 128 * 4);
    _Float16* Opart = (_Float16*)out;   // [8][tpc*128][512] fp16, fits 51.4 MB

    const size_t sXT = (size_t)THW * CCH;
    const size_t sG  = (size_t)DI * THW;

    pack_weights<<<2048, 256, 0, stream>>>(wt, wp, wg, wo, bt, bp, Wtp, Wg, Wo, btp);
    transpose_cast<<<dim3(THW / 32, CCH / 32, 2), 256, 0, stream>>>(x, xT);

    // theta|phi (t-major): tpg[t, m] = sum_c xT[t,c]*Wtp[m,c] + btp[m]
    gemm_nt<_Float16, 128, false, true, false, false, false><<<8 * 49 * 2, 256, 0, stream>>>(
        xT, CCH, sXT, Wtp, CCH, 0, tpg, 1024, sXT, CCH, CCH, 1.f,
        nullptr, btp, nullptr, nullptr, 0, 8, 49);

    // g (d-major): g[d, t] = sum_c Wg[d,c]*xT[t,c] + bg[d]
    gemm_nt<_Float16, 64, true, false, false, false, false><<<49 * 8 * 2, 256, 0, stream>>>(
        Wg, CCH, 0, xT, CCH, sXT, g, THW, sG, CCH, CCH, 1.f,
        bg, nullptr, nullptr, nullptr, 0, 49, 8);

    const float scale = 0.044194173824159216f;  // 512^-0.5
    for (int ch = 0; ch < nch; ch++) {
        int tile0 = ch * tpc;
        int tiles = (49 - tile0 < tpc) ? (49 - tile0) : tpc;
        size_t t0 = (size_t)tile0 * 128;
        int tchRows = tiles * 128;

        // expS[t,p] = exp(scale * sum_d theta[t,d]*phi[p,d]); psum partials
        gemm_nt<_Float16, 128, false, false, true, false, false><<<49 * tiles * 2, 256, 0, stream>>>(
            tpg + t0 * 1024, 1024, sXT, tpg + 512, 1024, sXT,
            S, THW, (size_t)tchRows * THW, DI, DI, scale,
            nullptr, nullptr, psum, nullptr, tchRows, 49, tiles);

        rowsum_inv<<<(2 * tchRows + 255) / 256, 256, 0, stream>>>(psum, inv, 2 * tchRows);

        // Opart[zz][t][d] = inv[t] * sum_{p in split ks} expS[t,p]*g[d,p]
        // split-K=4 (uneven: 1600,1600,1600,1472), normalized fp16 partials
        gemm_nt<_Float16, 128, false, false, false, false, true><<<4 * tiles * 8, 256, 0, stream>>>(
            S, THW, (size_t)tchRows * THW, g, THW, sG,
            Opart, DI, (size_t)tchRows * DI, 1600, THW, 1.f,
            nullptr, nullptr, nullptr, inv, tchRows, 4, tiles);

        // Ot[t,d] = f16( sum_ks Opart[ks*2+n][t][d] )
        combine4<<<(tchRows * 128 + 255) / 256, 256, 0, stream>>>(
            Opart, Ot, tchRows, (int)t0);
    }

    // Pc[c,t] = sum_d Wo[c,d]*Ot[t,d] + bo[c]; emits per-block GroupNorm stats
    gemm_nt<float, 128, true, false, false, true, false><<<49 * 8 * 2, 256, 0, stream>>>(
        Wo, DI, 0, Ot, DI, sG, out, THW, (size_t)CCH * THW, DI, DI, 1.f,
        bo, nullptr, gnp, nullptr, 0, 49, 8);

    reduce_final<<<2, 256, 0, stream>>>(gnp, stats, 392);
    final_residual<<<2048, 256, 0, stream>>>(x, out, stats, (size_t)2 * CCH * THW / 4);
}